// Round 3
// baseline (48.576 us; speedup 1.0000x reference)
//
#include <hip/hip_runtime.h>
#include <math.h>

typedef _Float16 half8 __attribute__((ext_vector_type(8)));
typedef float f32x4 __attribute__((ext_vector_type(4)));

#define RLT (1.0f/0.07f)

// out layout (flat fp32):
//   A      [256,196]  @ 0
//   logits [256,258]  @ 50176
//   Pos    [256,196]  @ 116224
//   Neg    [256,196]  @ 166400
//   A0_ref [256,256]  @ 216576

__device__ __forceinline__ void gll16(const void* g, void* l) {
    __builtin_amdgcn_global_load_lds(
        (const __attribute__((address_space(1))) void*)g,
        (__attribute__((address_space(3))) void*)l, 16, 0, 0);
}

// aud_pk layout: [c>>3][m][c&7] fp16 — 64 groups x 256 m x 8 halves (16B per (cg,m))
__global__ __launch_bounds__(256) void prep_aud_pk(const float* __restrict__ aud,
                                                   _Float16* __restrict__ aud_pk) {
    int m = blockIdx.x, t = threadIdx.x;
    float a0 = aud[m * 512 + t];
    float a1 = aud[m * 512 + 256 + t];
    float s = a0 * a0 + a1 * a1;
    #pragma unroll
    for (int off = 32; off; off >>= 1) s += __shfl_down(s, off, 64);
    __shared__ float wsum[4];
    __shared__ float rns;
    if ((t & 63) == 0) wsum[t >> 6] = s;
    __syncthreads();
    if (t == 0) rns = 1.0f / fmaxf(sqrtf(wsum[0] + wsum[1] + wsum[2] + wsum[3]), 1e-12f);
    __syncthreads();
    float rn = rns;
    int c0 = t, c1 = t + 256;
    aud_pk[(c0 >> 3) * 2048 + m * 8 + (c0 & 7)] = (_Float16)(a0 * rn);
    aud_pk[(c1 >> 3) * 2048 + m * 8 + (c1 & 7)] = (_Float16)(a1 * rn);
}

__global__ __launch_bounds__(512) void av_mfma2(const float* __restrict__ img,
                                                const _Float16* __restrict__ aud_pk,
                                                float* __restrict__ out) {
    const int n = blockIdx.x;
    const int tid = threadIdx.x;
    const int w = tid >> 6, l = tid & 63;
    const int q = w & 3;        // m-quarter: cols 64q..64q+63
    const int hh = w >> 2;      // hw half: 0 -> rows 0..111 (7 tiles), 1 -> 112..207 (6 tiles)
    const int HT = hh ? 6 : 7;

    __shared__ _Float16 __align__(16) Abuf[2][4][208][8];  // [buf][kg][hw][j]
    __shared__ _Float16 __align__(16) Bbuf[2][4][256][8];  // [buf][kg][m][j]
    __shared__ float rnorm_s[208];
    __shared__ float nrm_parts[2][196];
    __shared__ float red_max[2][256], red_sw[2][256], red_swa[2][256];
    __shared__ float diag_parts[2][4][4];

    // zero the pad rows (196..207) of both A buffers once (never overwritten)
    if (tid < 96) {
        int b = tid / 48, rem = tid % 48, kg = rem / 12, row = 196 + rem % 12;
        *(float4*)&Abuf[b][kg][row][0] = make_float4(0.f, 0.f, 0.f, 0.f);
    }

    const float* imgn = img + (size_t)n * (512 * 196);
    const bool act = tid < 392;            // A-staging threads: fixed hw, 16 consecutive c
    const int p   = act ? tid / 196 : 0;   // c sub-block (0: c 0..15, 1: c 16..31 of step)
    const int hws = act ? tid % 196 : 0;
    float nrm = 0.f;
    float av[16];

    // ---- B stage for K-step t into buf: pure linear 16B copies via global_load_lds
    // chunks e = w*64+l and 512+w*64+l of 1024; LDS dest wave-uniform base + lane*16
    #define STAGE_B(t, buf)                                                        \
        do {                                                                       \
            const _Float16* g0 = aud_pk + (((size_t)(t) * 1024 + w * 64 + l) << 3);\
            _Float16* l0 = &Bbuf[buf][0][0][0] + ((w * 64) << 3);                  \
            gll16(g0, l0);                                                         \
            gll16(g0 + 4096, l0 + 4096);                                           \
        } while (0)

    // ---- A convert+write into buf (data in av[]), accumulate norm
    #define STAGE_A(buf)                                                           \
        do {                                                                       \
            if (act) {                                                             \
                half8 h0, h1;                                                      \
                _Pragma("unroll")                                                  \
                for (int i = 0; i < 8; i++) {                                      \
                    h0[i] = (_Float16)av[i];                                       \
                    h1[i] = (_Float16)av[8 + i];                                   \
                    nrm += av[i] * av[i] + av[8 + i] * av[8 + i];                   \
                }                                                                  \
                *(half8*)&Abuf[buf][2 * p][hws][0]     = h0;                       \
                *(half8*)&Abuf[buf][2 * p + 1][hws][0] = h1;                       \
            }                                                                      \
        } while (0)

    // ---- prologue: stage K-step 0 into buf 0
    STAGE_B(0, 0);
    if (act) {
        const float* src = imgn + (size_t)(p * 16) * 196 + hws;
        #pragma unroll
        for (int i = 0; i < 16; i++) av[i] = src[i * 196];
    }
    STAGE_A(0);
    __syncthreads();

    f32x4 acc[7][4];
    #pragma unroll
    for (int ht = 0; ht < 7; ht++)
        #pragma unroll
        for (int mt = 0; mt < 4; mt++)
            acc[ht][mt] = (f32x4){0.f, 0.f, 0.f, 0.f};

    // per-lane LDS fragment offsets (in halves)
    const int aoff = (l >> 4) * 1664 + (hh * 112 + (l & 15)) * 8;  // + ht*128
    const int boff = (l >> 4) * 2048 + (q * 64 + (l & 15)) * 8;    // + mt*128

    for (int t = 0; t < 16; t++) {
        const int cur = t & 1, nb = cur ^ 1;
        const bool more = t < 15;
        // issue next-step staging loads early (land under MFMA)
        if (more) {
            STAGE_B(t + 1, nb);
            if (act) {
                const float* src = imgn + (size_t)(32 * (t + 1) + p * 16) * 196 + hws;
                #pragma unroll
                for (int i = 0; i < 16; i++) av[i] = src[i * 196];
            }
        }
        // compute current K-step
        {
            const _Float16* Ab = &Abuf[cur][0][0][0];
            const _Float16* Bb = &Bbuf[cur][0][0][0];
            half8 bfrag[4];
            #pragma unroll
            for (int mt = 0; mt < 4; mt++) bfrag[mt] = *(const half8*)(Bb + boff + mt * 128);
            half8 afrag[7];
            #pragma unroll
            for (int ht = 0; ht < 7; ht++)
                if (ht < HT) afrag[ht] = *(const half8*)(Ab + aoff + ht * 128);
            #pragma unroll
            for (int ht = 0; ht < 7; ht++)
                if (ht < HT)
                    #pragma unroll
                    for (int mt = 0; mt < 4; mt++)
                        acc[ht][mt] = __builtin_amdgcn_mfma_f32_16x16x32_f16(
                            afrag[ht], bfrag[mt], acc[ht][mt], 0, 0, 0);
        }
        // write converted A data into the other buffer
        if (more) STAGE_A(nb);
        __syncthreads();
    }

    // ---- img row norms
    if (act) nrm_parts[p][hws] = nrm;
    __syncthreads();
    if (tid < 208) {
        float v = 0.f;
        if (tid < 196) {
            float s = nrm_parts[0][tid] + nrm_parts[1][tid];
            v = 1.0f / fmaxf(sqrtf(s), 1e-12f);
        }
        rnorm_s[tid] = v;
    }
    __syncthreads();

    // ---- fused epilogue: normalize, sigmoid-gate, pool, max, diag maps
    float mx[4], sw[4], swa[4];
    #pragma unroll
    for (int mt = 0; mt < 4; mt++) { mx[mt] = -1e30f; sw[mt] = 0.f; swa[mt] = 0.f; }
    float s1n = 0.f, s1d = 0.f, s2n = 0.f, s2d = 0.f;
    const int dmt = (n >> 4) & 3, dq = n >> 6, dl = n & 15;
    const bool isdiag = (q == dq) && ((l & 15) == dl);

    #pragma unroll
    for (int ht = 0; ht < 7; ht++) {
        if (ht < HT) {
            int rowb = hh * 112 + ht * 16 + ((l >> 4) << 2);
            #pragma unroll
            for (int r = 0; r < 4; r++) {
                int hw = rowb + r;
                float rn = rnorm_s[hw];
                bool valid = hw < 196;
                #pragma unroll
                for (int mt = 0; mt < 4; mt++) {
                    float a0 = acc[ht][mt][r] * rn;
                    if (valid) {
                        float wg = 1.0f / (1.0f + __expf((0.65f - a0) * (1.0f / 0.03f)));
                        mx[mt]  = fmaxf(mx[mt], a0);
                        sw[mt] += wg;
                        swa[mt] += wg * a0;
                        if (isdiag && mt == dmt) {
                            out[n * 196 + hw] = a0;                 // A
                            out[116224 + n * 196 + hw] = wg;        // Pos
                            float p2 = 1.0f / (1.0f + __expf((0.40f - a0) * (1.0f / 0.03f)));
                            float ng = 1.0f - p2;
                            out[166400 + n * 196 + hw] = ng;        // Neg
                            s1n += wg * a0; s1d += wg;
                            s2n += ng * a0; s2d += ng;
                        }
                    }
                }
            }
        }
    }

    // cross-lane reduce (row-groups 16 apart hold same m)
    #pragma unroll
    for (int mt = 0; mt < 4; mt++) {
        float m1 = mx[mt], v1 = sw[mt], v2 = swa[mt];
        m1 = fmaxf(m1, __shfl_xor(m1, 16, 64)); v1 += __shfl_xor(v1, 16, 64); v2 += __shfl_xor(v2, 16, 64);
        m1 = fmaxf(m1, __shfl_xor(m1, 32, 64)); v1 += __shfl_xor(v1, 32, 64); v2 += __shfl_xor(v2, 32, 64);
        if (l < 16) {
            int m = q * 64 + mt * 16 + l;
            red_max[hh][m] = m1; red_sw[hh][m] = v1; red_swa[hh][m] = v2;
        }
    }
    if (isdiag) {
        diag_parts[hh][l >> 4][0] = s1n;
        diag_parts[hh][l >> 4][1] = s1d;
        diag_parts[hh][l >> 4][2] = s2n;
        diag_parts[hh][l >> 4][3] = s2d;
    }
    __syncthreads();

    if (tid < 256) {
        int m = tid;
        float mxv = fmaxf(red_max[0][m], red_max[1][m]);
        float num = red_swa[0][m] + red_swa[1][m];
        float den = red_sw[0][m] + red_sw[1][m];
        float sim = num / den;
        if (m == n) sim *= -99.0f;
        out[50176 + n * 258 + 1 + m] = sim * RLT;
        out[216576 + n * 256 + m] = mxv;
        if (m == n) {
            float t1n = 0.f, t1d = 0.f, t2n = 0.f, t2d = 0.f;
            #pragma unroll
            for (int h2 = 0; h2 < 2; h2++)
                #pragma unroll
                for (int g = 0; g < 4; g++) {
                    t1n += diag_parts[h2][g][0]; t1d += diag_parts[h2][g][1];
                    t2n += diag_parts[h2][g][2]; t2d += diag_parts[h2][g][3];
                }
            out[50176 + n * 258]       = (t1n / t1d) * RLT;
            out[50176 + n * 258 + 257] = (t2n / t2d) * RLT;
        }
    }
}

extern "C" void kernel_launch(void* const* d_in, const int* in_sizes, int n_in,
                              void* d_out, int out_size, void* d_ws, size_t ws_size,
                              hipStream_t stream) {
    const float* img = (const float*)d_in[0];
    const float* aud = (const float*)d_in[1];
    float* out = (float*)d_out;
    _Float16* aud_pk = (_Float16*)d_ws;   // 512*256 fp16 = 256 KB

    prep_aud_pk<<<256, 256, 0, stream>>>(aud, aud_pk);
    av_mfma2<<<256, 512, 0, stream>>>(img, aud_pk, out);
}

// Round 4
// 42.783 us; speedup vs baseline: 1.1354x; 1.1354x over previous
//
#include <hip/hip_runtime.h>
#include <math.h>

typedef _Float16 half8 __attribute__((ext_vector_type(8)));
typedef float f32x4 __attribute__((ext_vector_type(4)));

#define RLT (1.0f/0.07f)

// out layout (flat fp32):
//   A      [256,196]  @ 0
//   logits [256,258]  @ 50176
//   Pos    [256,196]  @ 116224
//   Neg    [256,196]  @ 166400
//   A0_ref [256,256]  @ 216576

__device__ __forceinline__ void gll16(const void* g, void* l) {
    __builtin_amdgcn_global_load_lds(
        (const __attribute__((address_space(1))) void*)g,
        (__attribute__((address_space(3))) void*)l, 16, 0, 0);
}

// aud_pk layout: [c>>3][m][c&7] fp16 — 64 groups x 256 m x 8 halves (16B per (cg,m))
__global__ __launch_bounds__(256) void prep_aud_pk(const float* __restrict__ aud,
                                                   _Float16* __restrict__ aud_pk) {
    int m = blockIdx.x, t = threadIdx.x;
    float a0 = aud[m * 512 + t];
    float a1 = aud[m * 512 + 256 + t];
    float s = a0 * a0 + a1 * a1;
    #pragma unroll
    for (int off = 32; off; off >>= 1) s += __shfl_down(s, off, 64);
    __shared__ float wsum[4];
    __shared__ float rns;
    if ((t & 63) == 0) wsum[t >> 6] = s;
    __syncthreads();
    if (t == 0) rns = 1.0f / fmaxf(sqrtf(wsum[0] + wsum[1] + wsum[2] + wsum[3]), 1e-12f);
    __syncthreads();
    float rn = rns;
    int c0 = t, c1 = t + 256;
    aud_pk[(c0 >> 3) * 2048 + m * 8 + (c0 & 7)] = (_Float16)(a0 * rn);
    aud_pk[(c1 >> 3) * 2048 + m * 8 + (c1 & 7)] = (_Float16)(a1 * rn);
}

// One block per (n, hw-half). half0: hw 0..97, half1: hw 98..195; local rows padded to 112.
__global__ __launch_bounds__(512, 4) void av_split(const float* __restrict__ img,
                                                   const _Float16* __restrict__ aud_pk,
                                                   float* __restrict__ out,
                                                   float* __restrict__ pmax,
                                                   float* __restrict__ psw,
                                                   float* __restrict__ pswa,
                                                   float* __restrict__ pdiag) {
    const int bid = blockIdx.x;
    const int n = bid >> 1, half = bid & 1;
    const int tid = threadIdx.x;
    const int w = tid >> 6, l = tid & 63;
    const int q = w & 3;          // m-quarter: cols 64q..64q+63
    const int hg = w >> 2;        // hw-group: 0 -> rows 0..63 (4 tiles), 1 -> 64..111 (3 tiles)
    const int HT = hg ? 3 : 4;

    __shared__ _Float16 __align__(16) Abuf[2][4][112][8];  // [buf][kg][row][j]
    __shared__ _Float16 __align__(16) Bbuf[2][4][256][8];  // [buf][kg][m][j]
    __shared__ float nrm_parts[4][98];
    __shared__ float rnorm_s[112];
    __shared__ float red_max[2][256], red_sw[2][256], red_swa[2][256];
    __shared__ float diag_parts[2][4][4];

    // zero the pad rows (98..111) of both A buffers once (never overwritten)
    if (tid < 112) {
        int b = tid / 56, rem = tid % 56, kg = rem / 14, row = 98 + rem % 14;
        *(float4*)&Abuf[b][kg][row][0] = make_float4(0.f, 0.f, 0.f, 0.f);
    }

    const float* imgn = img + (size_t)n * (512 * 196);
    const bool act = tid < 392;          // A-staging: fixed hw row, 8 consecutive c (one kg)
    const int p   = act ? tid / 98 : 0;  // kg within the 32-c step
    const int hwl = act ? tid % 98 : 0;  // local row
    const int g   = half * 98 + hwl;     // global hw
    float nrm = 0.f;
    float av[8];

    #define STAGE_B(t, buf)                                                         \
        do {                                                                        \
            const _Float16* g0 = aud_pk + (((size_t)(t) * 1024 + tid) << 3);        \
            _Float16* l0 = &Bbuf[buf][0][0][0] + ((w * 64) << 3);                   \
            gll16(g0, l0);                                                          \
            gll16(g0 + 4096, l0 + 4096);                                            \
        } while (0)

    #define LOAD_A(t)                                                               \
        do {                                                                        \
            if (act) {                                                              \
                const float* src = imgn + ((size_t)(32 * (t) + p * 8)) * 196 + g;   \
                _Pragma("unroll")                                                   \
                for (int i = 0; i < 8; i++) av[i] = src[i * 196];                   \
            }                                                                       \
        } while (0)

    #define STAGE_A(buf)                                                            \
        do {                                                                        \
            if (act) {                                                              \
                half8 h0;                                                           \
                _Pragma("unroll")                                                   \
                for (int i = 0; i < 8; i++) {                                       \
                    h0[i] = (_Float16)av[i];                                        \
                    nrm += av[i] * av[i];                                           \
                }                                                                   \
                *(half8*)&Abuf[buf][p][hwl][0] = h0;                                \
            }                                                                       \
        } while (0)

    // ---- prologue: stage K-step 0 into buf 0
    STAGE_B(0, 0);
    LOAD_A(0);
    STAGE_A(0);
    __syncthreads();

    f32x4 acc[4][4];
    #pragma unroll
    for (int ht = 0; ht < 4; ht++)
        #pragma unroll
        for (int mt = 0; mt < 4; mt++)
            acc[ht][mt] = (f32x4){0.f, 0.f, 0.f, 0.f};

    // per-lane LDS fragment offsets (in halves)
    const int aoff = (l >> 4) * 896  + (hg * 64 + (l & 15)) * 8;   // + ht*128
    const int boff = (l >> 4) * 2048 + (q * 64 + (l & 15)) * 8;    // + mt*128

    for (int t = 0; t < 16; t++) {
        const int cur = t & 1, nb = cur ^ 1;
        const bool more = t < 15;
        if (more) {
            STAGE_B(t + 1, nb);
            LOAD_A(t + 1);
        }
        {
            const _Float16* Ab = &Abuf[cur][0][0][0];
            const _Float16* Bb = &Bbuf[cur][0][0][0];
            half8 bfrag[4];
            #pragma unroll
            for (int mt = 0; mt < 4; mt++) bfrag[mt] = *(const half8*)(Bb + boff + mt * 128);
            half8 afrag[4];
            #pragma unroll
            for (int ht = 0; ht < 4; ht++)
                if (ht < HT) afrag[ht] = *(const half8*)(Ab + aoff + ht * 128);
            #pragma unroll
            for (int ht = 0; ht < 4; ht++)
                if (ht < HT)
                    #pragma unroll
                    for (int mt = 0; mt < 4; mt++)
                        acc[ht][mt] = __builtin_amdgcn_mfma_f32_16x16x32_f16(
                            afrag[ht], bfrag[mt], acc[ht][mt], 0, 0, 0);
        }
        if (more) STAGE_A(nb);
        __syncthreads();
    }

    // ---- img row norms (this block's rows only; each row fully covered: 4 kg x 8 c x 16 steps)
    if (act) nrm_parts[p][hwl] = nrm;
    __syncthreads();
    if (tid < 112) {
        float v = 0.f;
        if (tid < 98)
            v = 1.0f / fmaxf(sqrtf(nrm_parts[0][tid] + nrm_parts[1][tid] +
                                   nrm_parts[2][tid] + nrm_parts[3][tid]), 1e-12f);
        rnorm_s[tid] = v;
    }
    __syncthreads();

    // ---- fused epilogue
    float mx[4], sw[4], swa[4];
    #pragma unroll
    for (int mt = 0; mt < 4; mt++) { mx[mt] = -1e30f; sw[mt] = 0.f; swa[mt] = 0.f; }
    float s1n = 0.f, s1d = 0.f, s2n = 0.f, s2d = 0.f;
    const int dmt = (n >> 4) & 3, dq = n >> 6, dl = n & 15;
    const bool isdiag = (q == dq) && ((l & 15) == dl);

    #pragma unroll
    for (int ht = 0; ht < 4; ht++) {
        if (ht < HT) {
            int rowb = hg * 64 + ht * 16 + ((l >> 4) << 2);
            #pragma unroll
            for (int r = 0; r < 4; r++) {
                int row = rowb + r;
                float rn = rnorm_s[row];
                bool valid = row < 98;
                int hw = half * 98 + row;
                #pragma unroll
                for (int mt = 0; mt < 4; mt++) {
                    float a0 = acc[ht][mt][r] * rn;
                    if (valid) {
                        float wg = 1.0f / (1.0f + __expf((0.65f - a0) * (1.0f / 0.03f)));
                        mx[mt]  = fmaxf(mx[mt], a0);
                        sw[mt] += wg;
                        swa[mt] += wg * a0;
                        if (isdiag && mt == dmt) {
                            out[n * 196 + hw] = a0;                 // A
                            out[116224 + n * 196 + hw] = wg;        // Pos
                            float p2 = 1.0f / (1.0f + __expf((0.40f - a0) * (1.0f / 0.03f)));
                            float ng = 1.0f - p2;
                            out[166400 + n * 196 + hw] = ng;        // Neg
                            s1n += wg * a0; s1d += wg;
                            s2n += ng * a0; s2d += ng;
                        }
                    }
                }
            }
        }
    }

    // cross-lane reduce (lane groups 16 apart hold same m, different rows)
    #pragma unroll
    for (int mt = 0; mt < 4; mt++) {
        float m1 = mx[mt], v1 = sw[mt], v2 = swa[mt];
        m1 = fmaxf(m1, __shfl_xor(m1, 16, 64)); v1 += __shfl_xor(v1, 16, 64); v2 += __shfl_xor(v2, 16, 64);
        m1 = fmaxf(m1, __shfl_xor(m1, 32, 64)); v1 += __shfl_xor(v1, 32, 64); v2 += __shfl_xor(v2, 32, 64);
        if (l < 16) {
            int m = q * 64 + mt * 16 + l;
            red_max[hg][m] = m1; red_sw[hg][m] = v1; red_swa[hg][m] = v2;
        }
    }
    if (isdiag) {
        diag_parts[hg][l >> 4][0] = s1n;
        diag_parts[hg][l >> 4][1] = s1d;
        diag_parts[hg][l >> 4][2] = s2n;
        diag_parts[hg][l >> 4][3] = s2d;
    }
    __syncthreads();

    // ---- write per-(n,half) partials to workspace
    if (tid < 256) {
        int m = tid;
        int base = (n * 2 + half) * 256 + m;
        pmax[base] = fmaxf(red_max[0][m], red_max[1][m]);
        psw[base]  = red_sw[0][m] + red_sw[1][m];
        pswa[base] = red_swa[0][m] + red_swa[1][m];
    }
    if (tid < 4) {
        float s = 0.f;
        #pragma unroll
        for (int h2 = 0; h2 < 2; h2++)
            #pragma unroll
            for (int lg = 0; lg < 4; lg++)
                s += diag_parts[h2][lg][tid];
        pdiag[(n * 2 + half) * 4 + tid] = s;
    }
    #undef STAGE_B
    #undef LOAD_A
    #undef STAGE_A
}

__global__ __launch_bounds__(256) void av_final(const float* __restrict__ pmax,
                                                const float* __restrict__ psw,
                                                const float* __restrict__ pswa,
                                                const float* __restrict__ pdiag,
                                                float* __restrict__ out) {
    int n = blockIdx.x, m = threadIdx.x;
    int b0 = (n * 2) * 256 + m, b1 = (n * 2 + 1) * 256 + m;
    float mx = fmaxf(pmax[b0], pmax[b1]);
    float sim = (pswa[b0] + pswa[b1]) / (psw[b0] + psw[b1]);
    if (m == n) sim *= -99.0f;
    out[50176 + n * 258 + 1 + m] = sim * RLT;
    out[216576 + n * 256 + m] = mx;
    if (m == n) {
        const float* d = pdiag + n * 8;   // [half0: 4][half1: 4]
        out[50176 + n * 258]       = ((d[0] + d[4]) / (d[1] + d[5])) * RLT;
        out[50176 + n * 258 + 257] = ((d[2] + d[6]) / (d[3] + d[7])) * RLT;
    }
}

extern "C" void kernel_launch(void* const* d_in, const int* in_sizes, int n_in,
                              void* d_out, int out_size, void* d_ws, size_t ws_size,
                              hipStream_t stream) {
    const float* img = (const float*)d_in[0];
    const float* aud = (const float*)d_in[1];
    float* out = (float*)d_out;

    _Float16* aud_pk = (_Float16*)d_ws;          // 65536 halves = 128 KB... (256 KB region reserved)
    float* wsf   = (float*)d_ws;
    float* pmax  = wsf + 32768;                  // after aud_pk (131072 B)
    float* psw   = pmax + 131072;                // 256*2*256
    float* pswa  = psw + 131072;
    float* pdiag = pswa + 131072;                // 256*2*4
    // total ws use ≈ 1.71 MB

    prep_aud_pk<<<256, 256, 0, stream>>>(aud, aud_pk);
    av_split<<<512, 512, 0, stream>>>(img, aud_pk, out, pmax, psw, pswa, pdiag);
    av_final<<<256, 256, 0, stream>>>(pmax, psw, pswa, pdiag, out);
}